// Round 8
// baseline (157.346 us; speedup 1.0000x reference)
//
#include <hip/hip_runtime.h>

#define NT 256
#define BN_SHIFT 8           // 256 nodes per bucket
#define NBUCKET_MAX 512      // supports N <= 131072
#define CAP 8192             // dump/col slots per bucket (mean 4096, sd ~64)
#define EPB 2048             // edges per block in phase A (8/thread)

// ---------------------------------------------------------------------------
// prep: zero bucket cursors + pooled accumulators + batched weight chains.
// 6x128 chain matrix through W2..W5 (each chain enters at its layer), then
// fold through Wlin -> qv[6][10]. One block, 768 threads.
// ---------------------------------------------------------------------------
__global__ void __launch_bounds__(768)
prep_kernel(const float* __restrict__ W1, const float* __restrict__ b1,
            const float* __restrict__ W2, const float* __restrict__ b2,
            const float* __restrict__ W3, const float* __restrict__ b3,
            const float* __restrict__ W4, const float* __restrict__ b4,
            const float* __restrict__ W5, const float* __restrict__ b5,
            const float* __restrict__ Wlin, float* __restrict__ qout,
            int* __restrict__ gcur, int NB, float* __restrict__ pooled, int G) {
  __shared__ float cur[6][128];
  const int tid = threadIdx.x;
  for (int i = tid; i < NB; i += 768) gcur[i] = 0;       // replaces memset
  for (int i = tid; i < G * 5; i += 768) pooled[i] = 0.f; // re-zero every call
  const int vi = tid >> 7;   // wave-uniform
  const int t = tid & 127;
  float init;
  if (vi == 0) init = W1[t];
  else if (vi == 1) init = b1[t];
  else if (vi == 2) init = b2[t];
  else if (vi == 3) init = b3[t];
  else if (vi == 4) init = b4[t];
  else init = b5[t];
  cur[vi][t] = init;
  __syncthreads();
  const float* Ws[4] = {W2, W3, W4, W5};
  #pragma unroll
  for (int l = 0; l < 4; ++l) {
    const int nact = l + 2;           // chains 0..l+1 active at layer l
    float s = 0.f;
    if (vi < nact) {
      const float* __restrict__ W = Ws[l];
      #pragma unroll 8
      for (int k = 0; k < 128; ++k) s += cur[vi][k] * W[k * 128 + t];
    }
    __syncthreads();
    if (vi < nact) cur[vi][t] = s;
    __syncthreads();
  }
  if (tid < 60) {
    int v = tid / 10, c = tid % 10;
    float s = 0.f;
    for (int k = 0; k < 128; ++k) s += cur[v][k] * Wlin[k * 10 + c];
    qout[v * 10 + c] = s;
  }
}

// ---------------------------------------------------------------------------
// Phase A: bin edges by dst bucket. int4-vectorized ei reads; LDS count ->
// one global atomic per (block,bucket) -> packed dump (src<<8 | dst_local).
// EPB=2048 (782 blocks) for ~3 blocks/CU of store-latency hiding.
// ---------------------------------------------------------------------------
__global__ void binA_kernel(const int* __restrict__ ei, int* __restrict__ gcur,
                            unsigned int* __restrict__ dump, int E, int NB) {
  __shared__ unsigned int cnt[NBUCKET_MAX];
  __shared__ unsigned int base[NBUCKET_MAX];
  const int t = threadIdx.x;
  const int e0 = blockIdx.x * EPB;
  const bool vec_ok = ((E & 3) == 0);
  for (int b = t; b < NB; b += 256) cnt[b] = 0;
  __syncthreads();
  unsigned int slot[8];
  unsigned int dreg[8];
  #pragma unroll
  for (int jj = 0; jj < 2; ++jj) {
    int e = e0 + jj * 1024 + t * 4;
    if (vec_ok && e + 3 < E) {
      int4 d4 = *reinterpret_cast<const int4*>(&ei[E + e]);
      dreg[jj * 4 + 0] = (unsigned)d4.x;
      dreg[jj * 4 + 1] = (unsigned)d4.y;
      dreg[jj * 4 + 2] = (unsigned)d4.z;
      dreg[jj * 4 + 3] = (unsigned)d4.w;
      #pragma unroll
      for (int k = 0; k < 4; ++k)
        slot[jj * 4 + k] = atomicAdd(&cnt[dreg[jj * 4 + k] >> BN_SHIFT], 1u);
    } else {
      #pragma unroll
      for (int k = 0; k < 4; ++k) {
        int ee = e + k;
        if (ee < E) {
          unsigned d = (unsigned)ei[E + ee];
          dreg[jj * 4 + k] = d;
          slot[jj * 4 + k] = atomicAdd(&cnt[d >> BN_SHIFT], 1u);
        }
      }
    }
  }
  __syncthreads();
  for (int b = t; b < NB; b += 256) {
    unsigned int c = cnt[b];
    base[b] = c ? (unsigned int)atomicAdd(&gcur[b], (int)c) : 0u;
  }
  __syncthreads();
  #pragma unroll
  for (int jj = 0; jj < 2; ++jj) {
    int e = e0 + jj * 1024 + t * 4;
    unsigned s4v[4];
    bool fast = (vec_ok && e + 3 < E);
    if (fast) {
      int4 s4 = *reinterpret_cast<const int4*>(&ei[e]);
      s4v[0] = (unsigned)s4.x; s4v[1] = (unsigned)s4.y;
      s4v[2] = (unsigned)s4.z; s4v[3] = (unsigned)s4.w;
    }
    #pragma unroll
    for (int k = 0; k < 4; ++k) {
      int ee = e + k;
      if (ee < E) {
        unsigned s = fast ? s4v[k] : (unsigned)ei[ee];
        unsigned d = dreg[jj * 4 + k];
        unsigned b = d >> BN_SHIFT;
        unsigned pos = base[b] + slot[jj * 4 + k];
        if (pos < CAP)                   // overflow: 64-sigma event, dropped
          dump[(size_t)b * CAP + pos] = (s << BN_SHIFT) | (d & 255u);
      }
    }
  }
}

// ---------------------------------------------------------------------------
// Phase B: one block per bucket. Dump segment staged in registers (read once):
// LDS count -> LDS scan -> exact CSR placement into col segmented at b*CAP.
// Degree falls out -> fold init (dis2, sq, t0).
// ---------------------------------------------------------------------------
__global__ void binB_kernel(const unsigned int* __restrict__ dump,
                            const int* __restrict__ gcur,
                            const float* __restrict__ x, int* __restrict__ col,
                            int2* __restrict__ rl, float* __restrict__ dis2,
                            float* __restrict__ sq, float2* __restrict__ ta, int N) {
  __shared__ int cnt[256];
  __shared__ int sc[256];
  __shared__ int cur[256];
  const int b = blockIdx.x, t = threadIdx.x;
  cnt[t] = 0;
  __syncthreads();
  int total = gcur[b];
  if (total > CAP) total = CAP;
  const unsigned int* seg = dump + (size_t)b * CAP;
  unsigned wreg[CAP / 256];              // 32 regs, statically indexed
  #pragma unroll
  for (int k = 0; k < CAP / 256; ++k) {
    int i = (k << 8) + t;
    if (i < total) {
      unsigned w = seg[i];
      wreg[k] = w;
      atomicAdd(&cnt[w & 255u], 1);
    }
  }
  __syncthreads();
  int v = cnt[t];
  sc[t] = v;
  __syncthreads();
  for (int off = 1; off < 256; off <<= 1) {
    int u = (t >= off) ? sc[t - off] : 0;
    __syncthreads();
    sc[t] += u;
    __syncthreads();
  }
  int rbase = b * CAP + sc[t] - v;       // exclusive scan within bucket
  cur[t] = rbase;
  __syncthreads();
  #pragma unroll
  for (int k = 0; k < CAP / 256; ++k) {
    int i = (k << 8) + t;
    if (i < total) {
      unsigned w = wreg[k];
      int slot = atomicAdd(&cur[w & 255u], 1);
      col[slot] = (int)(w >> BN_SHIFT);
    }
  }
  int node = (b << BN_SHIFT) + t;
  if (node < N) {
    rl[node] = make_int2(rbase, v);
    float dis = rsqrtf((float)v + 1.0f);
    dis2[node] = dis * dis;
    sq[node] = 1.0f / dis;
    ta[node] = make_float2(dis * x[node], dis);
  }
}

// ---------------------------------------------------------------------------
// One propagation step, pure gather, 8 lanes per node, dual lookup chains:
//   tout[d] = dis2[d] * ( tin[d] + sum_{s in row(d)} tin[s] )
// Fused pooling: this pass's quantity (ones-chain for passes 1-4, x-chain for
// LAST) is reduced per graph in-block (batch sorted; ~2 atomics/block) into
// pooled[g*5 + slot]. LAST computes x-component only and writes no tout.
// ---------------------------------------------------------------------------
template <bool LAST>
__global__ void gather_kernel(const int* __restrict__ col, const int2* __restrict__ rl,
                              const float* __restrict__ dis2,
                              const float* __restrict__ sq,
                              const int* __restrict__ batch,
                              const float2* __restrict__ tin,
                              float2* __restrict__ tout,
                              float* __restrict__ pooled, int slot, int N) {
  __shared__ float sval[32];
  __shared__ int sg[32];
  int tid = blockIdx.x * blockDim.x + threadIdx.x;
  int node = tid >> 3, l8 = tid & 7;
  int nloc = threadIdx.x >> 3;
  bool valid = (node < N);
  float sx = 0.f, sy = 0.f;
  if (valid) {
    int2 r = rl[node];
    int j = l8;
    for (; j + 8 < r.y; j += 16) {       // two independent lookup chains
      int c0 = col[r.x + j];
      int c1 = col[r.x + j + 8];
      float2 a0 = tin[c0];
      float2 a1 = tin[c1];
      sx += a0.x + a1.x;
      if (!LAST) sy += a0.y + a1.y;
    }
    if (j < r.y) {
      float2 a = tin[col[r.x + j]];
      sx += a.x;
      if (!LAST) sy += a.y;
    }
  }
  sx += __shfl_xor(sx, 1);
  sx += __shfl_xor(sx, 2);
  sx += __shfl_xor(sx, 4);
  if (!LAST) {
    sy += __shfl_xor(sy, 1);
    sy += __shfl_xor(sy, 2);
    sy += __shfl_xor(sy, 4);
  }
  if (l8 == 0) {
    if (valid) {
      float2 ts = tin[node];
      float m = dis2[node];
      float ox = m * (sx + ts.x);
      float c;
      if (LAST) {
        c = ox * sq[node];               // x-chain pooled quantity; no tout
      } else {
        float oy = m * (sy + ts.y);
        tout[node] = make_float2(ox, oy);
        c = oy * sq[node];               // ones-chain pooled quantity
      }
      sval[nloc] = c;
      sg[nloc] = batch[node];
    } else {
      sval[nloc] = 0.f;
      sg[nloc] = -1;
    }
  }
  __syncthreads();
  if (threadIdx.x == 0) {                // run-length reduce (batch sorted)
    float acc = sval[0];
    int g = sg[0];
    #pragma unroll 4
    for (int i = 1; i < 32; ++i) {
      if (sg[i] == g) {
        acc += sval[i];
      } else {
        if (g >= 0) atomicAdd(&pooled[g * 5 + slot], acc);
        g = sg[i];
        acc = sval[i];
      }
    }
    if (g >= 0) atomicAdd(&pooled[g * 5 + slot], acc);
  }
}

// ---------------------------------------------------------------------------
// final: out[g][c] = sum_j pooled[g][j]/n_g * q[j*10+c] + q[50+c] + blin[c].
// One 64-thread block per graph; n_g from binary search (batch sorted).
// ---------------------------------------------------------------------------
__device__ __forceinline__ int lower_bound_i(const int* a, int n, int key) {
  int lo = 0, hi = n;
  while (lo < hi) {
    int mid = (lo + hi) >> 1;
    if (a[mid] < key) lo = mid + 1; else hi = mid;
  }
  return lo;
}

__global__ void final_kernel(const int* __restrict__ batch, int N,
                             const float* __restrict__ pooled,
                             const float* __restrict__ q,
                             const float* __restrict__ blin,
                             float* __restrict__ out) {
  int g = blockIdx.x;
  __shared__ int cntS;
  if (threadIdx.x == 0) {
    int lo = lower_bound_i(batch, N, g);
    int hi = lower_bound_i(batch, N, g + 1);
    cntS = hi - lo;
  }
  __syncthreads();
  int t = threadIdx.x;
  if (t < 10) {
    float inv = 1.0f / fmaxf((float)cntS, 1.0f);
    const float* pg = &pooled[g * 5];
    out[g * 10 + t] = (pg[0] * q[t] + pg[1] * q[10 + t] + pg[2] * q[20 + t] +
                       pg[3] * q[30 + t] + pg[4] * q[40 + t]) * inv +
                      q[50 + t] + blin[t];
  }
}

extern "C" void kernel_launch(void* const* d_in, const int* in_sizes, int n_in,
                              void* d_out, int out_size, void* d_ws, size_t ws_size,
                              hipStream_t stream) {
  const float* x    = (const float*)d_in[0];
  const int*   ei   = (const int*)d_in[1];   // [2][E], int32
  const int*   batch= (const int*)d_in[2];
  const float* W1   = (const float*)d_in[3];
  const float* b1   = (const float*)d_in[4];
  const float* W2   = (const float*)d_in[5];
  const float* b2   = (const float*)d_in[6];
  const float* W3   = (const float*)d_in[7];
  const float* b3   = (const float*)d_in[8];
  const float* W4   = (const float*)d_in[9];
  const float* b4   = (const float*)d_in[10];
  const float* W5   = (const float*)d_in[11];
  const float* b5   = (const float*)d_in[12];
  const float* Wlin = (const float*)d_in[13];
  const float* blin = (const float*)d_in[14];

  const int N  = in_sizes[0];       // 100000
  const int E  = in_sizes[1] / 2;   // 1600000
  const int G  = out_size / 10;     // 512
  const int NB = (N + 255) >> BN_SHIFT;

  // ---- workspace layout (4-byte units) ----
  float* ws = (float*)d_ws;
  size_t off = 0;
  float2* ta   = (float2*)(ws + off); off += 2 * (size_t)N;
  float2* tb   = (float2*)(ws + off); off += 2 * (size_t)N;
  float*  dis2 = ws + off;            off += N;
  float*  sq   = ws + off;            off += N;
  float*  pooled = ws + off;          off += (size_t)G * 5;
  float*  qv   = ws + off;            off += 64;
  if (off & 1) off++;                 // int2 alignment
  int2* rl     = (int2*)(ws + off);   off += 2 * (size_t)N;
  int* gcur    = (int*)(ws + off);    off += NB;
  if (off & 1) off++;
  unsigned int* dump = (unsigned int*)(ws + off); off += (size_t)NB * CAP;
  int* col     = (int*)(ws + off);    off += (size_t)NB * CAP;
  (void)ws_size;

  const int gridA = (E + EPB - 1) / EPB;
  const int gridG = (8 * N + NT - 1) / NT;

  // prep: zero cursors + pooled, weight chains (one dispatch)
  prep_kernel<<<1, 768, 0, stream>>>(W1, b1, W2, b2, W3, b3, W4, b4, W5, b5,
                                     Wlin, qv, gcur, NB, pooled, G);
  // build exact CSR: bin -> place (col segmented per bucket, no scan)
  binA_kernel<<<gridA, 256, 0, stream>>>(ei, gcur, dump, E, NB);
  binB_kernel<<<NB, 256, 0, stream>>>(dump, gcur, x, col, rl, dis2, sq, ta, N);

  // 5 propagation steps; pooling fused (pass k -> slot 5-k, last -> slot 0)
  gather_kernel<false><<<gridG, NT, 0, stream>>>(col, rl, dis2, sq, batch, ta, tb, pooled, 4, N);
  gather_kernel<false><<<gridG, NT, 0, stream>>>(col, rl, dis2, sq, batch, tb, ta, pooled, 3, N);
  gather_kernel<false><<<gridG, NT, 0, stream>>>(col, rl, dis2, sq, batch, ta, tb, pooled, 2, N);
  gather_kernel<false><<<gridG, NT, 0, stream>>>(col, rl, dis2, sq, batch, tb, ta, pooled, 1, N);
  gather_kernel<true ><<<gridG, NT, 0, stream>>>(col, rl, dis2, sq, batch, ta, nullptr, pooled, 0, N);

  final_kernel<<<G, 64, 0, stream>>>(batch, N, pooled, qv, blin, (float*)d_out);
}

// Round 9
// 116.108 us; speedup vs baseline: 1.3552x; 1.3552x over previous
//
#include <hip/hip_runtime.h>

#define NT 256
#define BN_SHIFT 8           // 256 nodes per bucket
#define NBUCKET_MAX 512      // supports N <= 131072
#define CAP 8192             // dump/col slots per bucket (mean 4096, sd ~64)
#define EPB 4096             // edges per block in phase A

// ---------------------------------------------------------------------------
// prep: zero bucket cursors + batched weight chains.
// 6x128 chain matrix through W2..W5. Latency-tuned: unroll-64 inner loops
// (2 HBM-latency rounds/layer) and a 480-thread k-split Wlin fold.
// ---------------------------------------------------------------------------
__global__ void __launch_bounds__(768)
prep_kernel(const float* __restrict__ W1, const float* __restrict__ b1,
            const float* __restrict__ W2, const float* __restrict__ b2,
            const float* __restrict__ W3, const float* __restrict__ b3,
            const float* __restrict__ W4, const float* __restrict__ b4,
            const float* __restrict__ W5, const float* __restrict__ b5,
            const float* __restrict__ Wlin, float* __restrict__ qout,
            int* __restrict__ gcur, int NB) {
  __shared__ float cur[6][128];
  __shared__ float red[6][10][8];
  const int tid = threadIdx.x;
  for (int i = tid; i < NB; i += 768) gcur[i] = 0;   // replaces hipMemsetAsync
  const int vi = tid >> 7;   // wave-uniform
  const int t = tid & 127;
  float init;
  if (vi == 0) init = W1[t];
  else if (vi == 1) init = b1[t];
  else if (vi == 2) init = b2[t];
  else if (vi == 3) init = b3[t];
  else if (vi == 4) init = b4[t];
  else init = b5[t];
  cur[vi][t] = init;
  __syncthreads();
  const float* Ws[4] = {W2, W3, W4, W5};
  #pragma unroll
  for (int l = 0; l < 4; ++l) {
    const int nact = l + 2;           // chains 0..l+1 active at layer l
    float s = 0.f;
    if (vi < nact) {
      const float* __restrict__ W = Ws[l];
      #pragma unroll 64
      for (int k = 0; k < 128; ++k) s += cur[vi][k] * W[k * 128 + t];
    }
    __syncthreads();
    if (vi < nact) cur[vi][t] = s;
    __syncthreads();
  }
  // Wlin fold: thread = (v, c, p); each p covers 16 k's (independent loads)
  if (tid < 480) {
    int v = tid / 80, rem = tid % 80, c = rem >> 3, pp = rem & 7;
    float s = 0.f;
    #pragma unroll
    for (int k = 0; k < 16; ++k) {
      int kk = pp * 16 + k;
      s += cur[v][kk] * Wlin[kk * 10 + c];
    }
    red[v][c][pp] = s;
  }
  __syncthreads();
  if (tid < 60) {
    int v = tid / 10, c = tid % 10;
    float s = 0.f;
    #pragma unroll
    for (int p = 0; p < 8; ++p) s += red[v][c][p];
    qout[v * 10 + c] = s;
  }
}

// ---------------------------------------------------------------------------
// Phase A: bin edges by dst bucket. int4-vectorized ei reads (each stream is
// read exactly once); LDS count -> one global atomic per (block,bucket)
// reserves dump space -> packed write (src<<8 | dst_local).
// ---------------------------------------------------------------------------
__global__ void binA_kernel(const int* __restrict__ ei, int* __restrict__ gcur,
                            unsigned int* __restrict__ dump, int E, int NB) {
  __shared__ unsigned int cnt[NBUCKET_MAX];
  __shared__ unsigned int base[NBUCKET_MAX];
  const int t = threadIdx.x;
  const int e0 = blockIdx.x * EPB;
  const bool vec_ok = ((E & 3) == 0);  // int4 paths need 16B alignment of ei+E
  for (int b = t; b < NB; b += 256) cnt[b] = 0;
  __syncthreads();
  unsigned int slot[16];
  unsigned int dreg[16];
  #pragma unroll
  for (int jj = 0; jj < 4; ++jj) {
    int e = e0 + jj * 1024 + t * 4;
    if (vec_ok && e + 3 < E) {
      int4 d4 = *reinterpret_cast<const int4*>(&ei[E + e]);
      dreg[jj * 4 + 0] = (unsigned)d4.x;
      dreg[jj * 4 + 1] = (unsigned)d4.y;
      dreg[jj * 4 + 2] = (unsigned)d4.z;
      dreg[jj * 4 + 3] = (unsigned)d4.w;
      #pragma unroll
      for (int k = 0; k < 4; ++k)
        slot[jj * 4 + k] = atomicAdd(&cnt[dreg[jj * 4 + k] >> BN_SHIFT], 1u);
    } else {
      #pragma unroll
      for (int k = 0; k < 4; ++k) {
        int ee = e + k;
        if (ee < E) {
          unsigned d = (unsigned)ei[E + ee];
          dreg[jj * 4 + k] = d;
          slot[jj * 4 + k] = atomicAdd(&cnt[d >> BN_SHIFT], 1u);
        }
      }
    }
  }
  __syncthreads();
  for (int b = t; b < NB; b += 256) {
    unsigned int c = cnt[b];
    base[b] = c ? (unsigned int)atomicAdd(&gcur[b], (int)c) : 0u;
  }
  __syncthreads();
  #pragma unroll
  for (int jj = 0; jj < 4; ++jj) {
    int e = e0 + jj * 1024 + t * 4;
    unsigned s4v[4];
    bool fast = (vec_ok && e + 3 < E);
    if (fast) {
      int4 s4 = *reinterpret_cast<const int4*>(&ei[e]);
      s4v[0] = (unsigned)s4.x; s4v[1] = (unsigned)s4.y;
      s4v[2] = (unsigned)s4.z; s4v[3] = (unsigned)s4.w;
    }
    #pragma unroll
    for (int k = 0; k < 4; ++k) {
      int ee = e + k;
      if (ee < E) {
        unsigned s = fast ? s4v[k] : (unsigned)ei[ee];
        unsigned d = dreg[jj * 4 + k];
        unsigned b = d >> BN_SHIFT;
        unsigned pos = base[b] + slot[jj * 4 + k];
        if (pos < CAP)                   // overflow: 64-sigma event, dropped
          dump[(size_t)b * CAP + pos] = (s << BN_SHIFT) | (d & 255u);
      }
    }
  }
}

// ---------------------------------------------------------------------------
// Phase B: one block per bucket. Dump segment staged in registers (read once):
// LDS count -> LDS scan -> exact CSR placement into col segmented at b*CAP.
// Degree falls out -> fold init (dis2, sq, t0).
// ---------------------------------------------------------------------------
__global__ void binB_kernel(const unsigned int* __restrict__ dump,
                            const int* __restrict__ gcur,
                            const float* __restrict__ x, int* __restrict__ col,
                            int2* __restrict__ rl, float* __restrict__ dis2,
                            float* __restrict__ sq, float2* __restrict__ ta, int N) {
  __shared__ int cnt[256];
  __shared__ int sc[256];
  __shared__ int cur[256];
  const int b = blockIdx.x, t = threadIdx.x;
  cnt[t] = 0;
  __syncthreads();
  int total = gcur[b];
  if (total > CAP) total = CAP;
  const unsigned int* seg = dump + (size_t)b * CAP;
  unsigned wreg[CAP / 256];              // 32 regs, statically indexed
  #pragma unroll
  for (int k = 0; k < CAP / 256; ++k) {
    int i = (k << 8) + t;
    if (i < total) {
      unsigned w = seg[i];
      wreg[k] = w;
      atomicAdd(&cnt[w & 255u], 1);
    }
  }
  __syncthreads();
  int v = cnt[t];
  sc[t] = v;
  __syncthreads();
  for (int off = 1; off < 256; off <<= 1) {
    int u = (t >= off) ? sc[t - off] : 0;
    __syncthreads();
    sc[t] += u;
    __syncthreads();
  }
  int rbase = b * CAP + sc[t] - v;       // exclusive scan within bucket
  cur[t] = rbase;
  __syncthreads();
  #pragma unroll
  for (int k = 0; k < CAP / 256; ++k) {
    int i = (k << 8) + t;
    if (i < total) {
      unsigned w = wreg[k];
      int slot = atomicAdd(&cur[w & 255u], 1);
      col[slot] = (int)(w >> BN_SHIFT);
    }
  }
  int node = (b << BN_SHIFT) + t;
  if (node < N) {
    rl[node] = make_int2(rbase, v);
    float dis = rsqrtf((float)v + 1.0f);
    dis2[node] = dis * dis;
    sq[node] = 1.0f / dis;
    ta[node] = make_float2(dis * x[node], dis);
  }
}

// ---------------------------------------------------------------------------
// One propagation step, pure gather, 8 lanes per node, dual lookup chains:
//   tout[d] = dis2[d] * ( tin[d] + sum_{s in row(d)} tin[s] )
// ssave (optional) records tout.y (this step's ones-chain value).
// ---------------------------------------------------------------------------
__global__ void gather_kernel(const int* __restrict__ col, const int2* __restrict__ rl,
                              const float* __restrict__ dis2,
                              const float2* __restrict__ tin, float2* __restrict__ tout,
                              float* __restrict__ ssave, int N) {
  int tid = blockIdx.x * blockDim.x + threadIdx.x;
  int node = tid >> 3, l8 = tid & 7;
  if (node >= N) return;
  int2 r = rl[node];
  float sx = 0.f, sy = 0.f;
  int j = l8;
  for (; j + 8 < r.y; j += 16) {         // two independent lookup chains
    int c0 = col[r.x + j];
    int c1 = col[r.x + j + 8];
    float2 a0 = tin[c0];
    float2 a1 = tin[c1];
    sx += a0.x + a1.x;
    sy += a0.y + a1.y;
  }
  if (j < r.y) {
    float2 a = tin[col[r.x + j]];
    sx += a.x;
    sy += a.y;
  }
  sx += __shfl_xor(sx, 1);
  sx += __shfl_xor(sx, 2);
  sx += __shfl_xor(sx, 4);
  sy += __shfl_xor(sy, 1);
  sy += __shfl_xor(sy, 2);
  sy += __shfl_xor(sy, 4);
  if (l8 == 0) {
    float2 ts = tin[node];
    float m = dis2[node];
    float oy = m * (sy + ts.y);
    tout[node] = make_float2(m * (sx + ts.x), oy);
    if (ssave) ssave[node] = oy;
  }
}

// ---------------------------------------------------------------------------
// Per-graph means of {t5.x, s4, s3, s2, s1} (unscaled by sq) + final matvec:
//   out[g][c] = m0 q0 + m1 q1 + m2 q2 + m3 q3 + m4 q4 + q5 + blin.
// batch sorted; one block per graph.
// ---------------------------------------------------------------------------
__device__ __forceinline__ int lower_bound_i(const int* a, int n, int key) {
  int lo = 0, hi = n;
  while (lo < hi) {
    int mid = (lo + hi) >> 1;
    if (a[mid] < key) lo = mid + 1; else hi = mid;
  }
  return lo;
}

__global__ void pool_kernel(const int* __restrict__ batch, int N,
                            const float2* __restrict__ t5, const float* __restrict__ s4,
                            const float* __restrict__ s3, const float* __restrict__ s2,
                            const float* __restrict__ s1, const float* __restrict__ sq,
                            const float* __restrict__ q, const float* __restrict__ blin,
                            float* __restrict__ out) {
  int g = blockIdx.x;
  __shared__ int sh[2];
  if (threadIdx.x == 0) {
    sh[0] = lower_bound_i(batch, N, g);
    sh[1] = lower_bound_i(batch, N, g + 1);
  }
  __syncthreads();
  int lo = sh[0], hi = sh[1];
  float a[5] = {0.f, 0.f, 0.f, 0.f, 0.f};
  for (int i = lo + threadIdx.x; i < hi; i += blockDim.x) {
    float qq = sq[i];
    a[0] += t5[i].x * qq;
    a[1] += s4[i] * qq;
    a[2] += s3[i] * qq;
    a[3] += s2[i] * qq;
    a[4] += s1[i] * qq;
  }
  __shared__ float red[4][5];
  __shared__ float m5[5];
  int lane = threadIdx.x & 63, wave = threadIdx.x >> 6;
  #pragma unroll
  for (int j = 0; j < 5; ++j)
    #pragma unroll
    for (int o = 32; o > 0; o >>= 1) a[j] += __shfl_down(a[j], o);
  if (lane == 0)
    #pragma unroll
    for (int j = 0; j < 5; ++j) red[wave][j] = a[j];
  __syncthreads();
  if (threadIdx.x == 0) {
    float denom = fmaxf((float)(hi - lo), 1.0f);
    #pragma unroll
    for (int j = 0; j < 5; ++j)
      m5[j] = (red[0][j] + red[1][j] + red[2][j] + red[3][j]) / denom;
  }
  __syncthreads();
  int t = threadIdx.x;
  if (t < 10) {
    out[g * 10 + t] = m5[0] * q[t] + m5[1] * q[10 + t] + m5[2] * q[20 + t] +
                      m5[3] * q[30 + t] + m5[4] * q[40 + t] + q[50 + t] + blin[t];
  }
}

extern "C" void kernel_launch(void* const* d_in, const int* in_sizes, int n_in,
                              void* d_out, int out_size, void* d_ws, size_t ws_size,
                              hipStream_t stream) {
  const float* x    = (const float*)d_in[0];
  const int*   ei   = (const int*)d_in[1];   // [2][E], int32
  const int*   batch= (const int*)d_in[2];
  const float* W1   = (const float*)d_in[3];
  const float* b1   = (const float*)d_in[4];
  const float* W2   = (const float*)d_in[5];
  const float* b2   = (const float*)d_in[6];
  const float* W3   = (const float*)d_in[7];
  const float* b3   = (const float*)d_in[8];
  const float* W4   = (const float*)d_in[9];
  const float* b4   = (const float*)d_in[10];
  const float* W5   = (const float*)d_in[11];
  const float* b5   = (const float*)d_in[12];
  const float* Wlin = (const float*)d_in[13];
  const float* blin = (const float*)d_in[14];

  const int N  = in_sizes[0];       // 100000
  const int E  = in_sizes[1] / 2;   // 1600000
  const int G  = out_size / 10;     // 512
  const int NB = (N + 255) >> BN_SHIFT;

  // ---- workspace layout (4-byte units) ----
  float* ws = (float*)d_ws;
  size_t off = 0;
  float2* ta   = (float2*)(ws + off); off += 2 * (size_t)N;
  float2* tb   = (float2*)(ws + off); off += 2 * (size_t)N;
  float*  dis2 = ws + off;            off += N;
  float*  sq   = ws + off;            off += N;
  float*  s1   = ws + off;            off += N;
  float*  s2   = ws + off;            off += N;
  float*  s3   = ws + off;            off += N;
  float*  s4   = ws + off;            off += N;
  float*  qv   = ws + off;            off += 64;
  if (off & 1) off++;                 // int2 alignment
  int2* rl     = (int2*)(ws + off);   off += 2 * (size_t)N;
  int* gcur    = (int*)(ws + off);    off += NB;
  if (off & 1) off++;
  unsigned int* dump = (unsigned int*)(ws + off); off += (size_t)NB * CAP;
  int* col     = (int*)(ws + off);    off += (size_t)NB * CAP;
  (void)ws_size;

  const int gridA = (E + EPB - 1) / EPB;
  const int gridG = (8 * N + NT - 1) / NT;

  // prep: zero cursors + weight chains (one dispatch)
  prep_kernel<<<1, 768, 0, stream>>>(W1, b1, W2, b2, W3, b3, W4, b4, W5, b5,
                                     Wlin, qv, gcur, NB);
  // build exact CSR: bin -> place (col segmented per bucket, no scan)
  binA_kernel<<<gridA, 256, 0, stream>>>(ei, gcur, dump, E, NB);
  binB_kernel<<<NB, 256, 0, stream>>>(dump, gcur, x, col, rl, dis2, sq, ta, N);

  // 5 fused propagation steps (x-chain and ones-chain together)
  gather_kernel<<<gridG, NT, 0, stream>>>(col, rl, dis2, ta, tb, s1, N);
  gather_kernel<<<gridG, NT, 0, stream>>>(col, rl, dis2, tb, ta, s2, N);
  gather_kernel<<<gridG, NT, 0, stream>>>(col, rl, dis2, ta, tb, s3, N);
  gather_kernel<<<gridG, NT, 0, stream>>>(col, rl, dis2, tb, ta, s4, N);
  gather_kernel<<<gridG, NT, 0, stream>>>(col, rl, dis2, ta, tb, nullptr, N);
  // t5 now in tb

  pool_kernel<<<G, 256, 0, stream>>>(batch, N, tb, s4, s3, s2, s1, sq, qv, blin,
                                     (float*)d_out);
}